// Round 5
// baseline (463.181 us; speedup 1.0000x reference)
//
#include <hip/hip_runtime.h>
#include <hip/hip_bf16.h>

#define NB 8
#define CH 256
#define MTOT 16384            // 4*4096 rows
#define ROWSTRIDE 2048        // NB*CH floats per row
#define BM 128
#define KSTEPS 8              // 256/32
#define LDSPITCH 40           // 32 + 8 ushort pad: b128 slot stride 5 mod 8 -> 2-way max (free, m136)
#define ABUF 10240            // ushorts per LDS buffer (2 mats * 128 rows * 40)
#define AIOFF 5120            // imag tile offset within buffer (128*40)
#define OFFI 33554432l        // 16384*2048, start of out_i in d_out

typedef __attribute__((ext_vector_type(8))) short bf16x8;
typedef __attribute__((ext_vector_type(4))) float f32x4;

__device__ inline short f2bf(float f) {
    union { float f; unsigned u; } x{f};
    unsigned r = x.u + 0x7fff + ((x.u >> 16) & 1);   // RNE
    return (short)(r >> 16);
}

// ---------------------------------------------------------------------------
// prep: w[mat][b][d][k] f32  ->  wT[mat][b][kc][n][ksub] bf16  (d=kc*32+ksub, n=k)
// grid 512 blocks x 256 thr; each block transposes one (mat,b,kc,nc) 32x64 tile
// ---------------------------------------------------------------------------
__global__ void prep_w(const float* __restrict__ wr, const float* __restrict__ wi,
                       unsigned short* __restrict__ wT) {
    int blk = blockIdx.x;
    int mat = blk >> 8;
    int idx = blk & 255;
    int nc = idx & 3, kc = (idx >> 2) & 7, b = idx >> 5;
    const float* w = mat ? wi : wr;
    __shared__ float tile[32][65];
    int t = threadIdx.x;
    int dd = t >> 3;            // 0..31
    int nn = (t & 7) * 8;       // 0..56
    const float* src = w + (((size_t)b * 256 + kc * 32 + dd) * 256 + nc * 64 + nn);
#pragma unroll
    for (int j = 0; j < 8; ++j) tile[dd][nn + j] = src[j];
    __syncthreads();
    int n = t >> 2;             // 0..63
    int ds = (t & 3) * 8;       // 0,8,16,24
    bf16x8 p;
#pragma unroll
    for (int j = 0; j < 8; ++j) p[j] = f2bf(tile[ds + j][n]);
    unsigned short* dst = wT + (size_t)mat * 524288 + b * 65536 + kc * 8192
                             + (nc * 64 + n) * 32 + ds;
    *(bf16x8*)dst = p;
}

// ---------------------------------------------------------------------------
// complex block GEMM: out_r = Ar*Wr - Ai*Wi + br ; out_i = Ar*Wi + Ai*Wr + bi
// grid = (MTOT/BM)*NB, 512 threads (8 waves: 2 row x 4 col, 64x64 tile / matrix).
// A: fp32->bf16 inline, LDS double-buffered, ONE barrier per K-step.
// W: bf16 fragments loaded directly from L2 (1KB/wave coalesced), reg dbuf.
// b = bid&7 == XCD id under round-robin: each XCD's L2 holds its 256KB W slice;
// A reads / out writes are disjoint per b -> no cross-XCD duplication.
// ---------------------------------------------------------------------------
__launch_bounds__(512, 2)
__global__ void cgemm(const float* __restrict__ Ar, const float* __restrict__ Ai,
                      const unsigned short* __restrict__ wT,
                      const float* __restrict__ br, const float* __restrict__ bi,
                      float* __restrict__ out) {
    int bid = blockIdx.x;
    int b  = bid & 7;
    int mt = bid >> 3;

    __shared__ unsigned short lds[2 * ABUF];   // 40 KB: [buf][mat][128][40]

    int t = threadIdx.x;
    int lane = t & 63;
    int wv = t >> 6;
    int wr_ = wv >> 2;          // 0..1
    int wc_ = wv & 3;           // 0..3
    int lrow = lane & 15;
    int kseg = lane >> 4;       // 0..3

    // A staging: 512 thr = 128 rows x 4 eight-float segments (128B/row/wave-quad)
    int srow = t >> 2;
    int sseg = t & 3;
    const size_t a_base = (size_t)(mt * BM + srow) * ROWSTRIDE + b * CH + sseg * 8;

    // W fragment base for this lane: + mat*524288 + kk*8192 + nf*512
    const unsigned short* wbase = wT + (size_t)b * 65536
                                     + (wc_ * 64 + lrow) * 32 + kseg * 8;

    f32x4 accr[4][4] = {};
    f32x4 acci[4][4] = {};

    f32x4 rR0, rR1, rI0, rI1;           // A prefetch regs (consumed same iter)
    bf16x8 rwr[2][4], rwi[2][4];        // W fragment double buffer

#define LOADA(K) { const float* p = Ar + a_base + (size_t)(K) * 32;              \
                   rR0 = *(const f32x4*)p;  rR1 = *(const f32x4*)(p + 4);        \
                   const float* q = Ai + a_base + (size_t)(K) * 32;              \
                   rI0 = *(const f32x4*)q;  rI1 = *(const f32x4*)(q + 4); }
#define LOADW(SEL, K) {                                                          \
    const unsigned short* p = wbase + (size_t)(K) * 8192;                        \
    rwr[SEL][0] = *(const bf16x8*)p;                                             \
    rwr[SEL][1] = *(const bf16x8*)(p + 512);                                     \
    rwr[SEL][2] = *(const bf16x8*)(p + 1024);                                    \
    rwr[SEL][3] = *(const bf16x8*)(p + 1536);                                    \
    rwi[SEL][0] = *(const bf16x8*)(p + 524288);                                  \
    rwi[SEL][1] = *(const bf16x8*)(p + 524800);                                  \
    rwi[SEL][2] = *(const bf16x8*)(p + 525312);                                  \
    rwi[SEL][3] = *(const bf16x8*)(p + 525824); }
#define STAGEA(BUF) {                                                            \
    bf16x8 pr, pi;                                                               \
    _Pragma("unroll")                                                            \
    for (int j = 0; j < 4; ++j) { pr[j] = f2bf(rR0[j]); pr[j + 4] = f2bf(rR1[j]);\
                                  pi[j] = f2bf(rI0[j]); pi[j + 4] = f2bf(rI1[j]);}\
    int d0 = (BUF) * ABUF + srow * LDSPITCH + sseg * 8;                          \
    *(bf16x8*)&lds[d0]         = pr;                                             \
    *(bf16x8*)&lds[d0 + AIOFF] = pi; }

    // prologue
    LOADA(0);
    LOADW(0, 0);
    STAGEA(0);

#pragma unroll
    for (int kk = 0; kk < KSTEPS; ++kk) {
        __syncthreads();                         // buf[kk&1] writes visible
        if (kk + 1 < KSTEPS) {
            LOADA(kk + 1);                       // HBM prefetch, lands under MFMAs
            LOADW((kk + 1) & 1, kk + 1);         // L2 prefetch, lands under MFMAs
        }
        int ab = (kk & 1) * ABUF;
#pragma unroll
        for (int mf = 0; mf < 4; ++mf) {
            int off = ab + (wr_ * 64 + mf * 16 + lrow) * LDSPITCH + kseg * 8;
            bf16x8 ar = *(const bf16x8*)&lds[off];
            bf16x8 ai = *(const bf16x8*)&lds[off + AIOFF];
            bf16x8 ain = ai ^ (short)0x8000;     // -imag via sign flip
#pragma unroll
            for (int nf = 0; nf < 4; ++nf) {
                accr[mf][nf] = __builtin_amdgcn_mfma_f32_16x16x32_bf16(ar,  rwr[kk & 1][nf], accr[mf][nf], 0, 0, 0);
                accr[mf][nf] = __builtin_amdgcn_mfma_f32_16x16x32_bf16(ain, rwi[kk & 1][nf], accr[mf][nf], 0, 0, 0);
                acci[mf][nf] = __builtin_amdgcn_mfma_f32_16x16x32_bf16(ar,  rwi[kk & 1][nf], acci[mf][nf], 0, 0, 0);
                acci[mf][nf] = __builtin_amdgcn_mfma_f32_16x16x32_bf16(ai,  rwr[kk & 1][nf], acci[mf][nf], 0, 0, 0);
            }
        }
        if (kk + 1 < KSTEPS) STAGEA((kk + 1) & 1);   // write other buffer; barrier at
                                                     // top of next iter protects RAW/WAR
    }

    // ---- epilogue: bias + store (C/D: col=lane&15, row=(lane>>4)*4+j, m89/m91) ----
    int colb = wc_ * 64 + lrow;
    int rbase = mt * BM + wr_ * 64 + (lane >> 4) * 4;
#pragma unroll
    for (int nf = 0; nf < 4; ++nf) {
        int col = colb + nf * 16;
        float brv = br[b * CH + col];
        float biv = bi[b * CH + col];
#pragma unroll
        for (int mf = 0; mf < 4; ++mf) {
            size_t ro = (size_t)(rbase + mf * 16) * ROWSTRIDE + b * CH + col;
#pragma unroll
            for (int j = 0; j < 4; ++j) {
                out[ro + (size_t)j * ROWSTRIDE]        = accr[mf][nf][j] + brv;
                out[OFFI + ro + (size_t)j * ROWSTRIDE] = acci[mf][nf][j] + biv;
            }
        }
    }
#undef LOADA
#undef LOADW
#undef STAGEA
}

extern "C" void kernel_launch(void* const* d_in, const int* in_sizes, int n_in,
                              void* d_out, int out_size, void* d_ws, size_t ws_size,
                              hipStream_t stream) {
    const float* real = (const float*)d_in[0];
    const float* imag = (const float*)d_in[1];
    const float* w_r  = (const float*)d_in[2];
    const float* w_i  = (const float*)d_in[3];
    const float* b_r  = (const float*)d_in[4];
    const float* b_i  = (const float*)d_in[5];
    float* out = (float*)d_out;
    unsigned short* wT = (unsigned short*)d_ws;   // 2 MB: [2][8][8][256][32] bf16

    prep_w<<<512, 256, 0, stream>>>(w_r, w_i, wT);
    cgemm<<<(MTOT / BM) * NB, 512, 0, stream>>>(real, imag, wT, b_r, b_i, out);
}